// Round 14
// baseline (262.324 us; speedup 1.0000x reference)
//
#include <hip/hip_runtime.h>
#include <cstdint>
#include <cstddef>

#define Bdim 4
#define Tdim 2048
#define Cdim 1024

// scan geometry: block 1024 = 8 ch-groups (x4 channels) x SEG(128) segs of 16
#define SEG  128
#define LSEG (Tdim / SEG)

#define G1_K   1024
#define G1_N   6144
#define G1_NKT 32
#define G1_NWG 1536

typedef __attribute__((ext_vector_type(8))) short bf16x8;
typedef __attribute__((ext_vector_type(4))) float f32x4;

__device__ __forceinline__ unsigned short f2bf(float f) {
    unsigned int u = __float_as_uint(f);
    u += 0x7fffu + ((u >> 16) & 1u);
    return (unsigned short)(u >> 16);
}
__device__ __forceinline__ float bfu(unsigned short h) {
    return __uint_as_float((unsigned int)h << 16);
}
__device__ __forceinline__ float frcp(float x) {
    return __builtin_amdgcn_rcpf(x);
}

__device__ __forceinline__ void gload_lds16(const void* g, void* l) {
    __builtin_amdgcn_global_load_lds(
        (const __attribute__((address_space(1))) unsigned int*)g,
        (__attribute__((address_space(3))) unsigned int*)l,
        16, 0, 0);
}

// ---------------------------------------------------------------------------
// merged fp32 -> bf16 cast of x, rkv_w, out_w
// ---------------------------------------------------------------------------
__global__ __launch_bounds__(256) void cast_all(
    const float* __restrict__ x,  unsigned short* __restrict__ xb,  int n1,
    const float* __restrict__ w1, unsigned short* __restrict__ wb,  int n2,
    const float* __restrict__ w2, unsigned short* __restrict__ ob,  int n3)
{
    int i = blockIdx.x * 256 + threadIdx.x;
    const float* in; unsigned short* out;
    if (i < n1)           { in = x;  out = xb; }
    else if (i < n1 + n2) { in = w1; out = wb; i -= n1; }
    else if (i < n1 + n2 + n3) { in = w2; out = ob; i -= n1 + n2; }
    else return;
    float4 v = ((const float4*)in)[i];
    ushort4 o;
    o.x = f2bf(v.x); o.y = f2bf(v.y); o.z = f2bf(v.z); o.w = f2bf(v.w);
    ((ushort4*)out)[i] = o;
}

// ---------------------------------------------------------------------------
// GEMM1: 256x128 tile, BK=32, 3-slot LDS rotation, 2 blocks/CU, XCD-chunked
// 2D tile order (R11/R12-verified). Unchanged.
// ---------------------------------------------------------------------------
__device__ __forceinline__ void stage_128(
    const unsigned short* __restrict__ G, int row0, int K, int elemoff,
    char* slot, int wave, int lane)
{
    const int sl = (lane & 3) ^ ((lane >> 3) & 3);
    const unsigned short* gp = G + (size_t)(row0 + wave * 16 + (lane >> 2)) * K
                                 + elemoff + sl * 8;
    gload_lds16(gp, slot + wave * 1024);
}

__global__ __launch_bounds__(512, 4) void gemm1_3slot(
    const unsigned short* __restrict__ A, const unsigned short* __restrict__ B,
    unsigned short* __restrict__ C)
{
    __shared__ char ldsb[73728];

    const int tid  = threadIdx.x;
    const int wave = tid >> 6;
    const int lane = tid & 63;
    const int wm = wave >> 1;
    const int wn = wave & 1;
    const int fr = lane & 15;
    const int cswz = (((lane >> 4) ^ ((fr >> 1) & 3)) << 4);

    const int xcd = blockIdx.x & 7;
    const int li  = blockIdx.x >> 3;
    const int bx  = li >> 2;
    const int by  = xcd * 4 + (li & 3);
    const int m0 = by * 256;
    const int n0 = bx * 128;

    f32x4 acc[4][4] = {};

    stage_128(A, m0,       G1_K, 0,  ldsb + 0,            wave, lane);
    stage_128(A, m0 + 128, G1_K, 0,  ldsb + 8192,         wave, lane);
    stage_128(B, n0,       G1_K, 0,  ldsb + 49152,        wave, lane);
    stage_128(A, m0,       G1_K, 32, ldsb + 16384,        wave, lane);
    stage_128(A, m0 + 128, G1_K, 32, ldsb + 16384 + 8192, wave, lane);
    stage_128(B, n0,       G1_K, 32, ldsb + 49152 + 8192, wave, lane);
    asm volatile("s_waitcnt vmcnt(3)" ::: "memory");
    __builtin_amdgcn_s_barrier();
    __builtin_amdgcn_sched_barrier(0);

    int sR = 0;
    for (int t = 0; t < G1_NKT; ++t) {
        const int sW = (sR >= 1) ? sR - 1 : 2;
        int kst = t + 2; if (kst > G1_NKT - 1) kst = G1_NKT - 1;
        const int keoff = kst * 32;

        const char* Asl = ldsb + sR * 16384;
        const char* Bsl = ldsb + 49152 + sR * 8192;

        bf16x8 af[4], bq[4];
        #pragma unroll
        for (int i_ = 0; i_ < 4; ++i_)
            af[i_] = *(const bf16x8*)(Asl + (wm * 64 + i_ * 16 + fr) * 64 + cswz);
        #pragma unroll
        for (int j_ = 0; j_ < 4; ++j_)
            bq[j_] = *(const bf16x8*)(Bsl + (wn * 64 + j_ * 16 + fr) * 64 + cswz);

        stage_128(A, m0,       G1_K, keoff, ldsb + sW * 16384,        wave, lane);
        stage_128(A, m0 + 128, G1_K, keoff, ldsb + sW * 16384 + 8192, wave, lane);
        stage_128(B, n0,       G1_K, keoff, ldsb + 49152 + sW * 8192, wave, lane);

        __builtin_amdgcn_s_barrier();
        __builtin_amdgcn_sched_barrier(0);
        __builtin_amdgcn_s_setprio(1);
        #pragma unroll
        for (int i_ = 0; i_ < 4; ++i_)
            #pragma unroll
            for (int j_ = 0; j_ < 4; ++j_)
                acc[i_][j_] = __builtin_amdgcn_mfma_f32_16x16x32_bf16(
                    af[i_], bq[j_], acc[i_][j_], 0, 0, 0);
        __builtin_amdgcn_s_setprio(0);
        asm volatile("s_waitcnt vmcnt(3)" ::: "memory");
        __builtin_amdgcn_s_barrier();
        __builtin_amdgcn_sched_barrier(0);

        sR = (sR < 2) ? sR + 1 : 0;
    }

    #pragma unroll
    for (int i_ = 0; i_ < 4; ++i_) {
        const int row = m0 + wm * 64 + i_ * 16 + (lane >> 4) * 4;
        #pragma unroll
        for (int j_ = 0; j_ < 4; ++j_) {
            const int col = n0 + wn * 64 + j_ * 16 + fr;
            #pragma unroll
            for (int r = 0; r < 4; ++r)
                C[(size_t)(row + r) * G1_N + col] = f2bf(acc[i_][j_][r]);
        }
    }
}

// ---------------------------------------------------------------------------
// m97-structure 128x128 bf16 GEMM (NT), fp32 out — GEMM2 (grid 512).
// ---------------------------------------------------------------------------
__global__ __launch_bounds__(256) void gemm_bf16_nt(
    const unsigned short* __restrict__ A, const unsigned short* __restrict__ B,
    float* __restrict__ C, int M, int N, int K)
{
    __shared__ unsigned short As[128 * 32];
    __shared__ unsigned short Bs[128 * 32];

    const int tid  = threadIdx.x;
    const int wave = tid >> 6;
    const int lane = tid & 63;
    const int m0 = blockIdx.y * 128;
    const int n0 = blockIdx.x * 128;
    const int wr = wave >> 1, wc = wave & 1;

    const int srow = tid >> 2;
    const int scol = (tid & 3) * 8;
    const unsigned short* Ag = A + (size_t)(m0 + srow) * K + scol;
    const unsigned short* Bg = B + (size_t)(n0 + srow) * K + scol;
    char* AsW = (char*)As + wave * 1024;
    char* BsW = (char*)Bs + wave * 1024;

    f32x4 acc[4][4] = {};

    const int fr = lane & 15;
    const int fk = (lane >> 4) * 8;

    for (int k0 = 0; k0 < K; k0 += 32) {
        gload_lds16(Ag + k0,                  AsW);
        gload_lds16(Ag + k0 + (size_t)64 * K, AsW + 4096);
        gload_lds16(Bg + k0,                  BsW);
        gload_lds16(Bg + k0 + (size_t)64 * K, BsW + 4096);
        __syncthreads();

        bf16x8 af[4], bfr_[4];
        #pragma unroll
        for (int f = 0; f < 4; ++f) {
            af[f]   = *(const bf16x8*)&As[(wr * 64 + f * 16 + fr) * 32 + fk];
            bfr_[f] = *(const bf16x8*)&Bs[(wc * 64 + f * 16 + fr) * 32 + fk];
        }
        #pragma unroll
        for (int i = 0; i < 4; ++i)
            #pragma unroll
            for (int j = 0; j < 4; ++j)
                acc[i][j] = __builtin_amdgcn_mfma_f32_16x16x32_bf16(
                    af[i], bfr_[j], acc[i][j], 0, 0, 0);
        __syncthreads();
    }

    #pragma unroll
    for (int i = 0; i < 4; ++i) {
        const int row = m0 + wr * 64 + i * 16 + (lane >> 4) * 4;
        #pragma unroll
        for (int j = 0; j < 4; ++j) {
            const int col = n0 + wc * 64 + j * 16 + (lane & 15);
            #pragma unroll
            for (int r = 0; r < 4; ++r)
                C[(size_t)(row + r) * N + col] = acc[i][j][r];
        }
    }
}

// ---------------------------------------------------------------------------
// Segmented-parallel fused sigmoid(r)*WKV scan, bf16 in/out, VC=4, SEG=128.
// Block = 1024 thr = 8 ch-groups (32 channels) x 128 segments of LSEG=16.
// VC=4: each thread owns 4 adjacent channels (ushort4 8B loads, 64B granule
// per 8-thread group) -> 4 independent chains/thread (ILP-4 latency hiding);
// serial chain = 16 steps/pass (half of R12). Grid = 4*2*32 = 256 blocks
// = 16 waves/CU. In-block combine: 32 lanes x 128 steps. fp32 state;
// per-channel op order identical to R12 => identical output.
// ---------------------------------------------------------------------------
__global__ __launch_bounds__(1024) void wkv_scan_par(
    const unsigned short* __restrict__ rkv,
    const float* __restrict__ td,  const float* __restrict__ tf,
    const float* __restrict__ tdr, const float* __restrict__ tfr,
    unsigned short* __restrict__ outcat)
{
    __shared__ float sBn[SEG][32], sBd[SEG][32], sMb[SEG][32];

    const int tid = threadIdx.x;
    const int chg = tid & 7;             // channel group (4 channels)
    const int seg = tid >> 3;            // 0..127

    const int bi  = blockIdx.x;          // b(4) x dir(2) x cgroup(32)
    const int b   = bi >> 6;
    const int rem = bi & 63;
    const int dir = rem >> 5;
    const int cbase = (rem & 31) * 32;   // block's first channel
    const int c0  = cbase + chg * 4;     // this thread's channels c0..c0+3

    float w[4], u[4];
    #pragma unroll
    for (int ch = 0; ch < 4; ++ch) {
        w[ch] = -__expf(dir ? tdr[c0 + ch] : td[c0 + ch]);
        u[ch] = dir ? tfr[c0 + ch] : tf[c0 + ch];
    }

    const int strideT = 6 * Cdim;
    const int tstep   = dir ? -strideT : strideT;
    const int t0      = dir ? (Tdim - 1 - seg * LSEG) : (seg * LSEG);

    const unsigned short* pbase = rkv + ((size_t)b * Tdim + t0) * strideT + dir * 3 * Cdim + c0;

    const int PF = 8;

    // ---- phase 1: segment-local summary (k,v only), 4 channels ----
    float bn[4] = {0.f, 0.f, 0.f, 0.f};
    float bd[4] = {0.f, 0.f, 0.f, 0.f};
    float mb[4] = {-1e38f, -1e38f, -1e38f, -1e38f};
    {
        const unsigned short* q = pbase;
        ushort4 kk[PF], vv[PF];
        #pragma unroll
        for (int i = 0; i < PF; ++i) {
            kk[i] = *(const ushort4*)(q + Cdim);
            vv[i] = *(const ushort4*)(q + 2 * Cdim);
            q += tstep;
        }
        for (int t = 0; t < LSEG; t += PF) {
            ushort4 kn[PF], vn[PF];
            if (t + PF < LSEG) {
                #pragma unroll
                for (int i = 0; i < PF; ++i) {
                    kn[i] = *(const ushort4*)(q + Cdim);
                    vn[i] = *(const ushort4*)(q + 2 * Cdim);
                    q += tstep;
                }
            }
            #pragma unroll
            for (int i = 0; i < PF; ++i) {
                const float kf[4] = {bfu(kk[i].x), bfu(kk[i].y), bfu(kk[i].z), bfu(kk[i].w)};
                const float vf[4] = {bfu(vv[i].x), bfu(vv[i].y), bfu(vv[i].z), bfu(vv[i].w)};
                #pragma unroll
                for (int ch = 0; ch < 4; ++ch) {
                    const float mw = mb[ch] + w[ch];
                    const float mn = fmaxf(mw, kf[ch]);
                    const float e1 = __expf(mw - mn);
                    const float e2 = __expf(kf[ch] - mn);
                    bn[ch] = e1 * bn[ch] + e2 * vf[ch];
                    bd[ch] = e1 * bd[ch] + e2;
                    mb[ch] = mn;
                }
            }
            #pragma unroll
            for (int i = 0; i < PF; ++i) { kk[i] = kn[i]; vv[i] = vn[i]; }
        }
    }
    #pragma unroll
    for (int ch = 0; ch < 4; ++ch) {
        sBn[seg][chg * 4 + ch] = bn[ch];
        sBd[seg][chg * 4 + ch] = bd[ch];
        sMb[seg][chg * 4 + ch] = mb[ch];
    }
    __syncthreads();

    // ---- phase 2: exclusive combine over 128 segments (32 lanes) ----
    if (tid < 32) {
        const float wv = -__expf(dir ? tdr[cbase + tid] : td[cbase + tid]);
        const float a  = wv * (float)LSEG;
        float n = 0.f, d = 0.f, m = -1e38f;
        for (int s = 0; s < SEG; ++s) {
            const float tn = sBn[s][tid], tdn = sBd[s][tid], tm = sMb[s][tid];
            sBn[s][tid] = n; sBd[s][tid] = d; sMb[s][tid] = m;
            const float ma = m + a;
            const float mm = fmaxf(ma, tm);
            const float e1 = __expf(ma - mm);
            const float e2 = __expf(tm - mm);
            n = e1 * n + e2 * tn;
            d = e1 * d + e2 * tdn;
            m = mm;
        }
    }
    __syncthreads();

    // ---- phase 3: replay segment from prefix, emit outputs ----
    float num[4], den[4], mx[4];
    #pragma unroll
    for (int ch = 0; ch < 4; ++ch) {
        num[ch] = sBn[seg][chg * 4 + ch];
        den[ch] = sBd[seg][chg * 4 + ch];
        mx[ch]  = sMb[seg][chg * 4 + ch];
    }
    {
        const unsigned short* q = pbase;
        unsigned short* po = outcat + ((size_t)b * Tdim + t0) * (2 * Cdim) + dir * Cdim + c0;
        const int ostep = dir ? -(2 * Cdim) : (2 * Cdim);

        ushort4 rr[PF], kk[PF], vv[PF];
        #pragma unroll
        for (int i = 0; i < PF; ++i) {
            rr[i] = *(const ushort4*)(q);
            kk[i] = *(const ushort4*)(q + Cdim);
            vv[i] = *(const ushort4*)(q + 2 * Cdim);
            q += tstep;
        }
        for (int t = 0; t < LSEG; t += PF) {
            ushort4 rn[PF], kn[PF], vn[PF];
            if (t + PF < LSEG) {
                #pragma unroll
                for (int i = 0; i < PF; ++i) {
                    rn[i] = *(const ushort4*)(q);
                    kn[i] = *(const ushort4*)(q + Cdim);
                    vn[i] = *(const ushort4*)(q + 2 * Cdim);
                    q += tstep;
                }
            }
            #pragma unroll
            for (int i = 0; i < PF; ++i) {
                const float kf[4] = {bfu(kk[i].x), bfu(kk[i].y), bfu(kk[i].z), bfu(kk[i].w)};
                const float vf[4] = {bfu(vv[i].x), bfu(vv[i].y), bfu(vv[i].z), bfu(vv[i].w)};
                const float rf[4] = {bfu(rr[i].x), bfu(rr[i].y), bfu(rr[i].z), bfu(rr[i].w)};
                unsigned short oy[4];
                #pragma unroll
                for (int ch = 0; ch < 4; ++ch) {
                    const float ku = kf[ch] + u[ch];
                    const float m  = fmaxf(mx[ch], ku);
                    const float e1 = __expf(mx[ch] - m);
                    const float e2 = __expf(ku - m);
                    const float y  = (e1 * num[ch] + e2 * vf[ch]) * frcp(e1 * den[ch] + e2);
                    const float sr = frcp(1.0f + __expf(-rf[ch]));
                    oy[ch] = f2bf(sr * y);
                    const float mw  = mx[ch] + w[ch];
                    const float mn  = fmaxf(mw, kf[ch]);
                    const float e1s = __expf(mw - mn);
                    const float e2s = __expf(kf[ch] - mn);
                    num[ch] = e1s * num[ch] + e2s * vf[ch];
                    den[ch] = e1s * den[ch] + e2s;
                    mx[ch]  = mn;
                }
                ushort4 ow;
                ow.x = oy[0]; ow.y = oy[1]; ow.z = oy[2]; ow.w = oy[3];
                *(ushort4*)po = ow;
                po += ostep;
            }
            #pragma unroll
            for (int i = 0; i < PF; ++i) { rr[i] = rn[i]; kk[i] = kn[i]; vv[i] = vn[i]; }
        }
    }
}

// ---------------------------------------------------------------------------
extern "C" void kernel_launch(void* const* d_in, const int* in_sizes, int n_in,
                              void* d_out, int out_size, void* d_ws, size_t ws_size,
                              hipStream_t stream)
{
    const float* x    = (const float*)d_in[0];
    const float* rkvw = (const float*)d_in[1];
    const float* outw = (const float*)d_in[2];
    const float* td   = (const float*)d_in[3];
    const float* tf   = (const float*)d_in[4];
    const float* tdr  = (const float*)d_in[5];
    const float* tfr  = (const float*)d_in[6];
    float* out = (float*)d_out;

    const int M = Bdim * Tdim;   // 8192

    char* ws = (char*)d_ws;
    unsigned short* rkv = (unsigned short*)ws;                 //  96 MiB bf16 [B,T,6C]
    unsigned short* xb  = (unsigned short*)(ws + 100663296);   //  16 MiB bf16 x
    unsigned short* wb  = (unsigned short*)(ws + 117440512);   //  12 MiB bf16 rkv_w
    unsigned short* ob  = (unsigned short*)(ws + 130023424);   //   4 MiB bf16 out_w
    unsigned short* cat = (unsigned short*)(ws + 134217728);   //  32 MiB bf16 out_cat

    const int n1 = M * Cdim / 4;
    const int n2 = 6 * Cdim * Cdim / 4;
    const int n3 = Cdim * 2 * Cdim / 4;

    hipLaunchKernelGGL(cast_all, dim3((n1 + n2 + n3 + 255) / 256), dim3(256), 0, stream,
                       x, xb, n1, rkvw, wb, n2, outw, ob, n3);

    // GEMM1: 256x128 tile, 3-slot, 2 blocks/CU, 2D-chunked XCD order
    hipLaunchKernelGGL(gemm1_3slot, dim3(G1_NWG), dim3(512), 0, stream, xb, wb, rkv);

    // segmented-parallel fused sigmoid + bidirectional WKV scan (VC=4, SEG=128)
    hipLaunchKernelGGL(wkv_scan_par, dim3(Bdim * 2 * 32), dim3(1024), 0, stream,
                       rkv, td, tf, tdr, tfr, cat);

    // GEMM2 (m97 128², fp32 out): M=8192, N=1024, K=2048; grid 8x64=512
    hipLaunchKernelGGL(gemm_bf16_nt, dim3(Cdim / 128, M / 128), dim3(256), 0, stream,
                       cat, ob, out, M, Cdim, 2 * Cdim);
}

// Round 15
// 250.165 us; speedup vs baseline: 1.0486x; 1.0486x over previous
//
#include <hip/hip_runtime.h>
#include <cstdint>
#include <cstddef>

#define Bdim 4
#define Tdim 2048
#define Cdim 1024

// scan geometry: block 1024 = 16 ch-groups (x2 channels) x SEG(64) segs of 32
#define SEG  64
#define LSEG (Tdim / SEG)

#define G1_K   1024
#define G1_N   6144
#define G1_NKT 32
#define G1_NWG 1536

typedef __attribute__((ext_vector_type(8))) short bf16x8;
typedef __attribute__((ext_vector_type(4))) float f32x4;

__device__ __forceinline__ unsigned short f2bf(float f) {
    unsigned int u = __float_as_uint(f);
    u += 0x7fffu + ((u >> 16) & 1u);
    return (unsigned short)(u >> 16);
}
__device__ __forceinline__ float bf2f_lo(unsigned int u) {
    return __uint_as_float(u << 16);
}
__device__ __forceinline__ float bf2f_hi(unsigned int u) {
    return __uint_as_float(u & 0xffff0000u);
}
__device__ __forceinline__ float frcp(float x) {
    return __builtin_amdgcn_rcpf(x);
}

__device__ __forceinline__ void gload_lds16(const void* g, void* l) {
    __builtin_amdgcn_global_load_lds(
        (const __attribute__((address_space(1))) unsigned int*)g,
        (__attribute__((address_space(3))) unsigned int*)l,
        16, 0, 0);
}

// ---------------------------------------------------------------------------
// merged fp32 -> bf16 cast of x, rkv_w, out_w
// ---------------------------------------------------------------------------
__global__ __launch_bounds__(256) void cast_all(
    const float* __restrict__ x,  unsigned short* __restrict__ xb,  int n1,
    const float* __restrict__ w1, unsigned short* __restrict__ wb,  int n2,
    const float* __restrict__ w2, unsigned short* __restrict__ ob,  int n3)
{
    int i = blockIdx.x * 256 + threadIdx.x;
    const float* in; unsigned short* out;
    if (i < n1)           { in = x;  out = xb; }
    else if (i < n1 + n2) { in = w1; out = wb; i -= n1; }
    else if (i < n1 + n2 + n3) { in = w2; out = ob; i -= n1 + n2; }
    else return;
    float4 v = ((const float4*)in)[i];
    ushort4 o;
    o.x = f2bf(v.x); o.y = f2bf(v.y); o.z = f2bf(v.z); o.w = f2bf(v.w);
    ((ushort4*)out)[i] = o;
}

// ---------------------------------------------------------------------------
// GEMM1: 256x128 tile, BK=32, 3-slot LDS rotation, 2 blocks/CU, XCD-chunked
// 2D tile order (R11/R12-verified). Unchanged.
// ---------------------------------------------------------------------------
__device__ __forceinline__ void stage_128(
    const unsigned short* __restrict__ G, int row0, int K, int elemoff,
    char* slot, int wave, int lane)
{
    const int sl = (lane & 3) ^ ((lane >> 3) & 3);
    const unsigned short* gp = G + (size_t)(row0 + wave * 16 + (lane >> 2)) * K
                                 + elemoff + sl * 8;
    gload_lds16(gp, slot + wave * 1024);
}

__global__ __launch_bounds__(512, 4) void gemm1_3slot(
    const unsigned short* __restrict__ A, const unsigned short* __restrict__ B,
    unsigned short* __restrict__ C)
{
    __shared__ char ldsb[73728];

    const int tid  = threadIdx.x;
    const int wave = tid >> 6;
    const int lane = tid & 63;
    const int wm = wave >> 1;
    const int wn = wave & 1;
    const int fr = lane & 15;
    const int cswz = (((lane >> 4) ^ ((fr >> 1) & 3)) << 4);

    const int xcd = blockIdx.x & 7;
    const int li  = blockIdx.x >> 3;
    const int bx  = li >> 2;
    const int by  = xcd * 4 + (li & 3);
    const int m0 = by * 256;
    const int n0 = bx * 128;

    f32x4 acc[4][4] = {};

    stage_128(A, m0,       G1_K, 0,  ldsb + 0,            wave, lane);
    stage_128(A, m0 + 128, G1_K, 0,  ldsb + 8192,         wave, lane);
    stage_128(B, n0,       G1_K, 0,  ldsb + 49152,        wave, lane);
    stage_128(A, m0,       G1_K, 32, ldsb + 16384,        wave, lane);
    stage_128(A, m0 + 128, G1_K, 32, ldsb + 16384 + 8192, wave, lane);
    stage_128(B, n0,       G1_K, 32, ldsb + 49152 + 8192, wave, lane);
    asm volatile("s_waitcnt vmcnt(3)" ::: "memory");
    __builtin_amdgcn_s_barrier();
    __builtin_amdgcn_sched_barrier(0);

    int sR = 0;
    for (int t = 0; t < G1_NKT; ++t) {
        const int sW = (sR >= 1) ? sR - 1 : 2;
        int kst = t + 2; if (kst > G1_NKT - 1) kst = G1_NKT - 1;
        const int keoff = kst * 32;

        const char* Asl = ldsb + sR * 16384;
        const char* Bsl = ldsb + 49152 + sR * 8192;

        bf16x8 af[4], bq[4];
        #pragma unroll
        for (int i_ = 0; i_ < 4; ++i_)
            af[i_] = *(const bf16x8*)(Asl + (wm * 64 + i_ * 16 + fr) * 64 + cswz);
        #pragma unroll
        for (int j_ = 0; j_ < 4; ++j_)
            bq[j_] = *(const bf16x8*)(Bsl + (wn * 64 + j_ * 16 + fr) * 64 + cswz);

        stage_128(A, m0,       G1_K, keoff, ldsb + sW * 16384,        wave, lane);
        stage_128(A, m0 + 128, G1_K, keoff, ldsb + sW * 16384 + 8192, wave, lane);
        stage_128(B, n0,       G1_K, keoff, ldsb + 49152 + sW * 8192, wave, lane);

        __builtin_amdgcn_s_barrier();
        __builtin_amdgcn_sched_barrier(0);
        __builtin_amdgcn_s_setprio(1);
        #pragma unroll
        for (int i_ = 0; i_ < 4; ++i_)
            #pragma unroll
            for (int j_ = 0; j_ < 4; ++j_)
                acc[i_][j_] = __builtin_amdgcn_mfma_f32_16x16x32_bf16(
                    af[i_], bq[j_], acc[i_][j_], 0, 0, 0);
        __builtin_amdgcn_s_setprio(0);
        asm volatile("s_waitcnt vmcnt(3)" ::: "memory");
        __builtin_amdgcn_s_barrier();
        __builtin_amdgcn_sched_barrier(0);

        sR = (sR < 2) ? sR + 1 : 0;
    }

    #pragma unroll
    for (int i_ = 0; i_ < 4; ++i_) {
        const int row = m0 + wm * 64 + i_ * 16 + (lane >> 4) * 4;
        #pragma unroll
        for (int j_ = 0; j_ < 4; ++j_) {
            const int col = n0 + wn * 64 + j_ * 16 + fr;
            #pragma unroll
            for (int r = 0; r < 4; ++r)
                C[(size_t)(row + r) * G1_N + col] = f2bf(acc[i_][j_][r]);
        }
    }
}

// ---------------------------------------------------------------------------
// m97-structure 128x128 bf16 GEMM (NT), fp32 out — GEMM2 (grid 512).
// ---------------------------------------------------------------------------
__global__ __launch_bounds__(256) void gemm_bf16_nt(
    const unsigned short* __restrict__ A, const unsigned short* __restrict__ B,
    float* __restrict__ C, int M, int N, int K)
{
    __shared__ unsigned short As[128 * 32];
    __shared__ unsigned short Bs[128 * 32];

    const int tid  = threadIdx.x;
    const int wave = tid >> 6;
    const int lane = tid & 63;
    const int m0 = blockIdx.y * 128;
    const int n0 = blockIdx.x * 128;
    const int wr = wave >> 1, wc = wave & 1;

    const int srow = tid >> 2;
    const int scol = (tid & 3) * 8;
    const unsigned short* Ag = A + (size_t)(m0 + srow) * K + scol;
    const unsigned short* Bg = B + (size_t)(n0 + srow) * K + scol;
    char* AsW = (char*)As + wave * 1024;
    char* BsW = (char*)Bs + wave * 1024;

    f32x4 acc[4][4] = {};

    const int fr = lane & 15;
    const int fk = (lane >> 4) * 8;

    for (int k0 = 0; k0 < K; k0 += 32) {
        gload_lds16(Ag + k0,                  AsW);
        gload_lds16(Ag + k0 + (size_t)64 * K, AsW + 4096);
        gload_lds16(Bg + k0,                  BsW);
        gload_lds16(Bg + k0 + (size_t)64 * K, BsW + 4096);
        __syncthreads();

        bf16x8 af[4], bfr_[4];
        #pragma unroll
        for (int f = 0; f < 4; ++f) {
            af[f]   = *(const bf16x8*)&As[(wr * 64 + f * 16 + fr) * 32 + fk];
            bfr_[f] = *(const bf16x8*)&Bs[(wc * 64 + f * 16 + fr) * 32 + fk];
        }
        #pragma unroll
        for (int i = 0; i < 4; ++i)
            #pragma unroll
            for (int j = 0; j < 4; ++j)
                acc[i][j] = __builtin_amdgcn_mfma_f32_16x16x32_bf16(
                    af[i], bfr_[j], acc[i][j], 0, 0, 0);
        __syncthreads();
    }

    #pragma unroll
    for (int i = 0; i < 4; ++i) {
        const int row = m0 + wr * 64 + i * 16 + (lane >> 4) * 4;
        #pragma unroll
        for (int j = 0; j < 4; ++j) {
            const int col = n0 + wc * 64 + j * 16 + (lane & 15);
            #pragma unroll
            for (int r = 0; r < 4; ++r)
                C[(size_t)(row + r) * N + col] = acc[i][j][r];
        }
    }
}

// ---------------------------------------------------------------------------
// Segmented-parallel fused sigmoid(r)*WKV scan, bf16 in/out, VC=2, SEG=64.
// R12 geometry exactly (16 chg x 64 seg, 64B granules, 16 waves/CU).
// CHANGE vs R12: phase-3 prefetch depth PF3=4 (was 8) -> phase-3 live
// registers ~50 < the 64-VGPR cap of 1024-thr blocks -> no scratch spills
// in the hot loop (R14's regression isolated the spill mechanism).
// Per-channel op order identical to R12 => identical output.
// ---------------------------------------------------------------------------
__global__ __launch_bounds__(1024) void wkv_scan_par(
    const unsigned short* __restrict__ rkv,
    const float* __restrict__ td,  const float* __restrict__ tf,
    const float* __restrict__ tdr, const float* __restrict__ tfr,
    unsigned short* __restrict__ outcat)
{
    __shared__ float sBn[SEG][32], sBd[SEG][32], sMb[SEG][32];

    const int tid = threadIdx.x;
    const int chg = tid & 15;            // channel group (2 channels)
    const int seg = tid >> 4;            // 0..63

    const int bi  = blockIdx.x;          // b(4) x dir(2) x cgroup(32)
    const int b   = bi >> 6;
    const int rem = bi & 63;
    const int dir = rem >> 5;
    const int cbase = (rem & 31) * 32;   // block's first channel
    const int c0  = cbase + chg * 2;     // this thread's channels c0, c0+1

    const float w0 = -__expf(dir ? tdr[c0]     : td[c0]);
    const float w1 = -__expf(dir ? tdr[c0 + 1] : td[c0 + 1]);
    const float u0 = dir ? tfr[c0]     : tf[c0];
    const float u1 = dir ? tfr[c0 + 1] : tf[c0 + 1];

    const int strideT = 6 * Cdim;
    const int tstep   = dir ? -strideT : strideT;
    const int t0      = dir ? (Tdim - 1 - seg * LSEG) : (seg * LSEG);

    const unsigned short* pbase = rkv + ((size_t)b * Tdim + t0) * strideT + dir * 3 * Cdim + c0;

    // ---- phase 1: segment-local summary (k,v only), PF=8 ----
    float bn0 = 0.f, bd0 = 0.f, mb0 = -1e38f;
    float bn1 = 0.f, bd1 = 0.f, mb1 = -1e38f;
    {
        const int PF = 8;
        const unsigned short* q = pbase;
        unsigned int kk[PF], vv[PF];
        #pragma unroll
        for (int i = 0; i < PF; ++i) {
            kk[i] = *(const unsigned int*)(q + Cdim);
            vv[i] = *(const unsigned int*)(q + 2 * Cdim);
            q += tstep;
        }
        for (int t = 0; t < LSEG; t += PF) {
            unsigned int kn[PF], vn[PF];
            if (t + PF < LSEG) {
                #pragma unroll
                for (int i = 0; i < PF; ++i) {
                    kn[i] = *(const unsigned int*)(q + Cdim);
                    vn[i] = *(const unsigned int*)(q + 2 * Cdim);
                    q += tstep;
                }
            }
            #pragma unroll
            for (int i = 0; i < PF; ++i) {
                {
                    const float k_ = bf2f_lo(kk[i]), v_ = bf2f_lo(vv[i]);
                    const float mw = mb0 + w0;
                    const float mn = fmaxf(mw, k_);
                    const float e1 = __expf(mw - mn);
                    const float e2 = __expf(k_ - mn);
                    bn0 = e1 * bn0 + e2 * v_;
                    bd0 = e1 * bd0 + e2;
                    mb0 = mn;
                }
                {
                    const float k_ = bf2f_hi(kk[i]), v_ = bf2f_hi(vv[i]);
                    const float mw = mb1 + w1;
                    const float mn = fmaxf(mw, k_);
                    const float e1 = __expf(mw - mn);
                    const float e2 = __expf(k_ - mn);
                    bn1 = e1 * bn1 + e2 * v_;
                    bd1 = e1 * bd1 + e2;
                    mb1 = mn;
                }
            }
            #pragma unroll
            for (int i = 0; i < PF; ++i) { kk[i] = kn[i]; vv[i] = vn[i]; }
        }
    }
    sBn[seg][chg * 2] = bn0; sBd[seg][chg * 2] = bd0; sMb[seg][chg * 2] = mb0;
    sBn[seg][chg * 2 + 1] = bn1; sBd[seg][chg * 2 + 1] = bd1; sMb[seg][chg * 2 + 1] = mb1;
    __syncthreads();

    // ---- phase 2: exclusive combine over 64 segments (32 lanes) ----
    if (tid < 32) {
        const float wv = -__expf(dir ? tdr[cbase + tid] : td[cbase + tid]);
        const float a  = wv * (float)LSEG;
        float n = 0.f, d = 0.f, m = -1e38f;
        for (int s = 0; s < SEG; ++s) {
            const float tn = sBn[s][tid], tdn = sBd[s][tid], tm = sMb[s][tid];
            sBn[s][tid] = n; sBd[s][tid] = d; sMb[s][tid] = m;
            const float ma = m + a;
            const float mm = fmaxf(ma, tm);
            const float e1 = __expf(ma - mm);
            const float e2 = __expf(tm - mm);
            n = e1 * n + e2 * tn;
            d = e1 * d + e2 * tdn;
            m = mm;
        }
    }
    __syncthreads();

    // ---- phase 3: replay segment from prefix, emit outputs; PF=4 ----
    float num0 = sBn[seg][chg * 2],     den0 = sBd[seg][chg * 2],     mx0 = sMb[seg][chg * 2];
    float num1 = sBn[seg][chg * 2 + 1], den1 = sBd[seg][chg * 2 + 1], mx1 = sMb[seg][chg * 2 + 1];
    {
        const int PF = 4;
        const unsigned short* q = pbase;
        unsigned short* po = outcat + ((size_t)b * Tdim + t0) * (2 * Cdim) + dir * Cdim + c0;
        const int ostep = dir ? -(2 * Cdim) : (2 * Cdim);

        unsigned int rr[PF], kk[PF], vv[PF];
        #pragma unroll
        for (int i = 0; i < PF; ++i) {
            rr[i] = *(const unsigned int*)(q);
            kk[i] = *(const unsigned int*)(q + Cdim);
            vv[i] = *(const unsigned int*)(q + 2 * Cdim);
            q += tstep;
        }
        for (int t = 0; t < LSEG; t += PF) {
            unsigned int rn[PF], kn[PF], vn[PF];
            if (t + PF < LSEG) {
                #pragma unroll
                for (int i = 0; i < PF; ++i) {
                    rn[i] = *(const unsigned int*)(q);
                    kn[i] = *(const unsigned int*)(q + Cdim);
                    vn[i] = *(const unsigned int*)(q + 2 * Cdim);
                    q += tstep;
                }
            }
            #pragma unroll
            for (int i = 0; i < PF; ++i) {
                unsigned int ow;
                {
                    const float k_ = bf2f_lo(kk[i]), v_ = bf2f_lo(vv[i]), r_ = bf2f_lo(rr[i]);
                    const float ku = k_ + u0;
                    const float m  = fmaxf(mx0, ku);
                    const float e1 = __expf(mx0 - m);
                    const float e2 = __expf(ku - m);
                    const float y  = (e1 * num0 + e2 * v_) * frcp(e1 * den0 + e2);
                    const float sr = frcp(1.0f + __expf(-r_));
                    ow = (unsigned int)f2bf(sr * y);
                    const float mw  = mx0 + w0;
                    const float mn  = fmaxf(mw, k_);
                    const float e1s = __expf(mw - mn);
                    const float e2s = __expf(k_ - mn);
                    num0 = e1s * num0 + e2s * v_;
                    den0 = e1s * den0 + e2s;
                    mx0  = mn;
                }
                {
                    const float k_ = bf2f_hi(kk[i]), v_ = bf2f_hi(vv[i]), r_ = bf2f_hi(rr[i]);
                    const float ku = k_ + u1;
                    const float m  = fmaxf(mx1, ku);
                    const float e1 = __expf(mx1 - m);
                    const float e2 = __expf(ku - m);
                    const float y  = (e1 * num1 + e2 * v_) * frcp(e1 * den1 + e2);
                    const float sr = frcp(1.0f + __expf(-r_));
                    ow |= ((unsigned int)f2bf(sr * y)) << 16;
                    const float mw  = mx1 + w1;
                    const float mn  = fmaxf(mw, k_);
                    const float e1s = __expf(mw - mn);
                    const float e2s = __expf(k_ - mn);
                    num1 = e1s * num1 + e2s * v_;
                    den1 = e1s * den1 + e2s;
                    mx1  = mn;
                }
                *(unsigned int*)po = ow;
                po += ostep;
            }
            #pragma unroll
            for (int i = 0; i < PF; ++i) { rr[i] = rn[i]; kk[i] = kn[i]; vv[i] = vn[i]; }
        }
    }
}

// ---------------------------------------------------------------------------
extern "C" void kernel_launch(void* const* d_in, const int* in_sizes, int n_in,
                              void* d_out, int out_size, void* d_ws, size_t ws_size,
                              hipStream_t stream)
{
    const float* x    = (const float*)d_in[0];
    const float* rkvw = (const float*)d_in[1];
    const float* outw = (const float*)d_in[2];
    const float* td   = (const float*)d_in[3];
    const float* tf   = (const float*)d_in[4];
    const float* tdr  = (const float*)d_in[5];
    const float* tfr  = (const float*)d_in[6];
    float* out = (float*)d_out;

    const int M = Bdim * Tdim;   // 8192

    char* ws = (char*)d_ws;
    unsigned short* rkv = (unsigned short*)ws;                 //  96 MiB bf16 [B,T,6C]
    unsigned short* xb  = (unsigned short*)(ws + 100663296);   //  16 MiB bf16 x
    unsigned short* wb  = (unsigned short*)(ws + 117440512);   //  12 MiB bf16 rkv_w
    unsigned short* ob  = (unsigned short*)(ws + 130023424);   //   4 MiB bf16 out_w
    unsigned short* cat = (unsigned short*)(ws + 134217728);   //  32 MiB bf16 out_cat

    const int n1 = M * Cdim / 4;
    const int n2 = 6 * Cdim * Cdim / 4;
    const int n3 = Cdim * 2 * Cdim / 4;

    hipLaunchKernelGGL(cast_all, dim3((n1 + n2 + n3 + 255) / 256), dim3(256), 0, stream,
                       x, xb, n1, rkvw, wb, n2, outw, ob, n3);

    // GEMM1: 256x128 tile, 3-slot, 2 blocks/CU, 2D-chunked XCD order
    hipLaunchKernelGGL(gemm1_3slot, dim3(G1_NWG), dim3(512), 0, stream, xb, wb, rkv);

    // segmented-parallel fused sigmoid + bidirectional WKV scan (VC=2, SEG=64, PF3=4)
    hipLaunchKernelGGL(wkv_scan_par, dim3(Bdim * 2 * 32), dim3(1024), 0, stream,
                       rkv, td, tf, tdr, tfr, cat);

    // GEMM2 (m97 128², fp32 out): M=8192, N=1024, K=2048; grid 8x64=512
    hipLaunchKernelGGL(gemm_bf16_nt, dim3(Cdim / 128, M / 128), dim3(256), 0, stream,
                       cat, ob, out, M, Cdim, 2 * Cdim);
}

// Round 16
// 232.224 us; speedup vs baseline: 1.1296x; 1.0773x over previous
//
#include <hip/hip_runtime.h>
#include <cstdint>
#include <cstddef>

#define Bdim 4
#define Tdim 2048
#define Cdim 1024

// scan geometry: block 1024 = 16 ch-groups (x2 channels) x SEG(64) segs of 32
#define SEG  64
#define LSEG (Tdim / SEG)

#define G1_K   1024
#define G1_N   6144
#define G1_NKT 32
#define G1_NWG 1536

typedef __attribute__((ext_vector_type(8))) short bf16x8;
typedef __attribute__((ext_vector_type(4))) float f32x4;

__device__ __forceinline__ unsigned short f2bf(float f) {
    unsigned int u = __float_as_uint(f);
    u += 0x7fffu + ((u >> 16) & 1u);
    return (unsigned short)(u >> 16);
}
__device__ __forceinline__ float bf2f_lo(unsigned int u) {
    return __uint_as_float(u << 16);
}
__device__ __forceinline__ float bf2f_hi(unsigned int u) {
    return __uint_as_float(u & 0xffff0000u);
}
__device__ __forceinline__ float frcp(float x) {
    return __builtin_amdgcn_rcpf(x);
}

__device__ __forceinline__ void gload_lds16(const void* g, void* l) {
    __builtin_amdgcn_global_load_lds(
        (const __attribute__((address_space(1))) unsigned int*)g,
        (__attribute__((address_space(3))) unsigned int*)l,
        16, 0, 0);
}

// ---------------------------------------------------------------------------
// merged fp32 -> bf16 cast of x, rkv_w, out_w
// ---------------------------------------------------------------------------
__global__ __launch_bounds__(256) void cast_all(
    const float* __restrict__ x,  unsigned short* __restrict__ xb,  int n1,
    const float* __restrict__ w1, unsigned short* __restrict__ wb,  int n2,
    const float* __restrict__ w2, unsigned short* __restrict__ ob,  int n3)
{
    int i = blockIdx.x * 256 + threadIdx.x;
    const float* in; unsigned short* out;
    if (i < n1)           { in = x;  out = xb; }
    else if (i < n1 + n2) { in = w1; out = wb; i -= n1; }
    else if (i < n1 + n2 + n3) { in = w2; out = ob; i -= n1 + n2; }
    else return;
    float4 v = ((const float4*)in)[i];
    ushort4 o;
    o.x = f2bf(v.x); o.y = f2bf(v.y); o.z = f2bf(v.z); o.w = f2bf(v.w);
    ((ushort4*)out)[i] = o;
}

// ---------------------------------------------------------------------------
// GEMM1: 256x128 tile, BK=32, 3-slot LDS rotation, 2 blocks/CU, XCD-chunked
// 2D tile order (R11/R12-verified). Unchanged.
// ---------------------------------------------------------------------------
__device__ __forceinline__ void stage_128(
    const unsigned short* __restrict__ G, int row0, int K, int elemoff,
    char* slot, int wave, int lane)
{
    const int sl = (lane & 3) ^ ((lane >> 3) & 3);
    const unsigned short* gp = G + (size_t)(row0 + wave * 16 + (lane >> 2)) * K
                                 + elemoff + sl * 8;
    gload_lds16(gp, slot + wave * 1024);
}

__global__ __launch_bounds__(512, 4) void gemm1_3slot(
    const unsigned short* __restrict__ A, const unsigned short* __restrict__ B,
    unsigned short* __restrict__ C)
{
    __shared__ char ldsb[73728];

    const int tid  = threadIdx.x;
    const int wave = tid >> 6;
    const int lane = tid & 63;
    const int wm = wave >> 1;
    const int wn = wave & 1;
    const int fr = lane & 15;
    const int cswz = (((lane >> 4) ^ ((fr >> 1) & 3)) << 4);

    const int xcd = blockIdx.x & 7;
    const int li  = blockIdx.x >> 3;
    const int bx  = li >> 2;
    const int by  = xcd * 4 + (li & 3);
    const int m0 = by * 256;
    const int n0 = bx * 128;

    f32x4 acc[4][4] = {};

    stage_128(A, m0,       G1_K, 0,  ldsb + 0,            wave, lane);
    stage_128(A, m0 + 128, G1_K, 0,  ldsb + 8192,         wave, lane);
    stage_128(B, n0,       G1_K, 0,  ldsb + 49152,        wave, lane);
    stage_128(A, m0,       G1_K, 32, ldsb + 16384,        wave, lane);
    stage_128(A, m0 + 128, G1_K, 32, ldsb + 16384 + 8192, wave, lane);
    stage_128(B, n0,       G1_K, 32, ldsb + 49152 + 8192, wave, lane);
    asm volatile("s_waitcnt vmcnt(3)" ::: "memory");
    __builtin_amdgcn_s_barrier();
    __builtin_amdgcn_sched_barrier(0);

    int sR = 0;
    for (int t = 0; t < G1_NKT; ++t) {
        const int sW = (sR >= 1) ? sR - 1 : 2;
        int kst = t + 2; if (kst > G1_NKT - 1) kst = G1_NKT - 1;
        const int keoff = kst * 32;

        const char* Asl = ldsb + sR * 16384;
        const char* Bsl = ldsb + 49152 + sR * 8192;

        bf16x8 af[4], bq[4];
        #pragma unroll
        for (int i_ = 0; i_ < 4; ++i_)
            af[i_] = *(const bf16x8*)(Asl + (wm * 64 + i_ * 16 + fr) * 64 + cswz);
        #pragma unroll
        for (int j_ = 0; j_ < 4; ++j_)
            bq[j_] = *(const bf16x8*)(Bsl + (wn * 64 + j_ * 16 + fr) * 64 + cswz);

        stage_128(A, m0,       G1_K, keoff, ldsb + sW * 16384,        wave, lane);
        stage_128(A, m0 + 128, G1_K, keoff, ldsb + sW * 16384 + 8192, wave, lane);
        stage_128(B, n0,       G1_K, keoff, ldsb + 49152 + sW * 8192, wave, lane);

        __builtin_amdgcn_s_barrier();
        __builtin_amdgcn_sched_barrier(0);
        __builtin_amdgcn_s_setprio(1);
        #pragma unroll
        for (int i_ = 0; i_ < 4; ++i_)
            #pragma unroll
            for (int j_ = 0; j_ < 4; ++j_)
                acc[i_][j_] = __builtin_amdgcn_mfma_f32_16x16x32_bf16(
                    af[i_], bq[j_], acc[i_][j_], 0, 0, 0);
        __builtin_amdgcn_s_setprio(0);
        asm volatile("s_waitcnt vmcnt(3)" ::: "memory");
        __builtin_amdgcn_s_barrier();
        __builtin_amdgcn_sched_barrier(0);

        sR = (sR < 2) ? sR + 1 : 0;
    }

    #pragma unroll
    for (int i_ = 0; i_ < 4; ++i_) {
        const int row = m0 + wm * 64 + i_ * 16 + (lane >> 4) * 4;
        #pragma unroll
        for (int j_ = 0; j_ < 4; ++j_) {
            const int col = n0 + wn * 64 + j_ * 16 + fr;
            #pragma unroll
            for (int r = 0; r < 4; ++r)
                C[(size_t)(row + r) * G1_N + col] = f2bf(acc[i_][j_][r]);
        }
    }
}

// ---------------------------------------------------------------------------
// m97-structure 128x128 bf16 GEMM (NT), fp32 out — GEMM2 (grid 512).
// ---------------------------------------------------------------------------
__global__ __launch_bounds__(256) void gemm_bf16_nt(
    const unsigned short* __restrict__ A, const unsigned short* __restrict__ B,
    float* __restrict__ C, int M, int N, int K)
{
    __shared__ unsigned short As[128 * 32];
    __shared__ unsigned short Bs[128 * 32];

    const int tid  = threadIdx.x;
    const int wave = tid >> 6;
    const int lane = tid & 63;
    const int m0 = blockIdx.y * 128;
    const int n0 = blockIdx.x * 128;
    const int wr = wave >> 1, wc = wave & 1;

    const int srow = tid >> 2;
    const int scol = (tid & 3) * 8;
    const unsigned short* Ag = A + (size_t)(m0 + srow) * K + scol;
    const unsigned short* Bg = B + (size_t)(n0 + srow) * K + scol;
    char* AsW = (char*)As + wave * 1024;
    char* BsW = (char*)Bs + wave * 1024;

    f32x4 acc[4][4] = {};

    const int fr = lane & 15;
    const int fk = (lane >> 4) * 8;

    for (int k0 = 0; k0 < K; k0 += 32) {
        gload_lds16(Ag + k0,                  AsW);
        gload_lds16(Ag + k0 + (size_t)64 * K, AsW + 4096);
        gload_lds16(Bg + k0,                  BsW);
        gload_lds16(Bg + k0 + (size_t)64 * K, BsW + 4096);
        __syncthreads();

        bf16x8 af[4], bfr_[4];
        #pragma unroll
        for (int f = 0; f < 4; ++f) {
            af[f]   = *(const bf16x8*)&As[(wr * 64 + f * 16 + fr) * 32 + fk];
            bfr_[f] = *(const bf16x8*)&Bs[(wc * 64 + f * 16 + fr) * 32 + fk];
        }
        #pragma unroll
        for (int i = 0; i < 4; ++i)
            #pragma unroll
            for (int j = 0; j < 4; ++j)
                acc[i][j] = __builtin_amdgcn_mfma_f32_16x16x32_bf16(
                    af[i], bfr_[j], acc[i][j], 0, 0, 0);
        __syncthreads();
    }

    #pragma unroll
    for (int i = 0; i < 4; ++i) {
        const int row = m0 + wr * 64 + i * 16 + (lane >> 4) * 4;
        #pragma unroll
        for (int j = 0; j < 4; ++j) {
            const int col = n0 + wc * 64 + j * 16 + (lane & 15);
            #pragma unroll
            for (int r = 0; r < 4; ++r)
                C[(size_t)(row + r) * N + col] = acc[i][j][r];
        }
    }
}

// ---------------------------------------------------------------------------
// Segmented-parallel fused sigmoid(r)*WKV scan, bf16 in/out, VC=2, SEG=64.
// EXACT R12 (best, 244.1us): PF=8 in BOTH phases (~50 live VGPR < 64 cap,
// no spills). NEW vs R12: XCD pair-swizzle of blockIdx so the two blocks
// covering adjacent 64B halves of each 128B L2 line (cgroups 2j, 2j+1)
// land on the SAME XCD (perf-only remap; bijective).
// ---------------------------------------------------------------------------
__global__ __launch_bounds__(1024) void wkv_scan_par(
    const unsigned short* __restrict__ rkv,
    const float* __restrict__ td,  const float* __restrict__ tf,
    const float* __restrict__ tdr, const float* __restrict__ tfr,
    unsigned short* __restrict__ outcat)
{
    __shared__ float sBn[SEG][32], sBd[SEG][32], sMb[SEG][32];

    const int tid = threadIdx.x;
    const int chg = tid & 15;            // channel group (2 channels)
    const int seg = tid >> 4;            // 0..63

    // XCD pair-swizzle: assume blockIdx%8 -> XCD round-robin. Map so the
    // identity pairs (2p, 2p+1) sit at (xcd, 2s) and (xcd, 2s+1): both on
    // one XCD. id = pairidx*2 + parity, pairidx = (slot>>1)*8 + xcd.
    const int xcd  = blockIdx.x & 7;
    const int slot = blockIdx.x >> 3;            // 0..63
    const int bi   = (((slot >> 1) * 8 + xcd) << 1) | (slot & 1);

    const int b   = bi >> 6;
    const int rem = bi & 63;
    const int dir = rem >> 5;
    const int cbase = (rem & 31) * 32;   // block's first channel
    const int c0  = cbase + chg * 2;     // this thread's channels c0, c0+1

    const float w0 = -__expf(dir ? tdr[c0]     : td[c0]);
    const float w1 = -__expf(dir ? tdr[c0 + 1] : td[c0 + 1]);
    const float u0 = dir ? tfr[c0]     : tf[c0];
    const float u1 = dir ? tfr[c0 + 1] : tf[c0 + 1];

    const int strideT = 6 * Cdim;
    const int tstep   = dir ? -strideT : strideT;
    const int t0      = dir ? (Tdim - 1 - seg * LSEG) : (seg * LSEG);

    const unsigned short* pbase = rkv + ((size_t)b * Tdim + t0) * strideT + dir * 3 * Cdim + c0;

    const int PF = 8;

    // ---- phase 1: segment-local summary (k,v only) ----
    float bn0 = 0.f, bd0 = 0.f, mb0 = -1e38f;
    float bn1 = 0.f, bd1 = 0.f, mb1 = -1e38f;
    {
        const unsigned short* q = pbase;
        unsigned int kk[PF], vv[PF];
        #pragma unroll
        for (int i = 0; i < PF; ++i) {
            kk[i] = *(const unsigned int*)(q + Cdim);
            vv[i] = *(const unsigned int*)(q + 2 * Cdim);
            q += tstep;
        }
        for (int t = 0; t < LSEG; t += PF) {
            unsigned int kn[PF], vn[PF];
            if (t + PF < LSEG) {
                #pragma unroll
                for (int i = 0; i < PF; ++i) {
                    kn[i] = *(const unsigned int*)(q + Cdim);
                    vn[i] = *(const unsigned int*)(q + 2 * Cdim);
                    q += tstep;
                }
            }
            #pragma unroll
            for (int i = 0; i < PF; ++i) {
                {
                    const float k_ = bf2f_lo(kk[i]), v_ = bf2f_lo(vv[i]);
                    const float mw = mb0 + w0;
                    const float mn = fmaxf(mw, k_);
                    const float e1 = __expf(mw - mn);
                    const float e2 = __expf(k_ - mn);
                    bn0 = e1 * bn0 + e2 * v_;
                    bd0 = e1 * bd0 + e2;
                    mb0 = mn;
                }
                {
                    const float k_ = bf2f_hi(kk[i]), v_ = bf2f_hi(vv[i]);
                    const float mw = mb1 + w1;
                    const float mn = fmaxf(mw, k_);
                    const float e1 = __expf(mw - mn);
                    const float e2 = __expf(k_ - mn);
                    bn1 = e1 * bn1 + e2 * v_;
                    bd1 = e1 * bd1 + e2;
                    mb1 = mn;
                }
            }
            #pragma unroll
            for (int i = 0; i < PF; ++i) { kk[i] = kn[i]; vv[i] = vn[i]; }
        }
    }
    sBn[seg][chg * 2] = bn0; sBd[seg][chg * 2] = bd0; sMb[seg][chg * 2] = mb0;
    sBn[seg][chg * 2 + 1] = bn1; sBd[seg][chg * 2 + 1] = bd1; sMb[seg][chg * 2 + 1] = mb1;
    __syncthreads();

    // ---- phase 2: exclusive combine over 64 segments (32 lanes) ----
    if (tid < 32) {
        const float wv = -__expf(dir ? tdr[cbase + tid] : td[cbase + tid]);
        const float a  = wv * (float)LSEG;
        float n = 0.f, d = 0.f, m = -1e38f;
        for (int s = 0; s < SEG; ++s) {
            const float tn = sBn[s][tid], tdn = sBd[s][tid], tm = sMb[s][tid];
            sBn[s][tid] = n; sBd[s][tid] = d; sMb[s][tid] = m;
            const float ma = m + a;
            const float mm = fmaxf(ma, tm);
            const float e1 = __expf(ma - mm);
            const float e2 = __expf(tm - mm);
            n = e1 * n + e2 * tn;
            d = e1 * d + e2 * tdn;
            m = mm;
        }
    }
    __syncthreads();

    // ---- phase 3: replay segment from prefix, emit outputs (PF=8) ----
    float num0 = sBn[seg][chg * 2],     den0 = sBd[seg][chg * 2],     mx0 = sMb[seg][chg * 2];
    float num1 = sBn[seg][chg * 2 + 1], den1 = sBd[seg][chg * 2 + 1], mx1 = sMb[seg][chg * 2 + 1];
    {
        const unsigned short* q = pbase;
        unsigned short* po = outcat + ((size_t)b * Tdim + t0) * (2 * Cdim) + dir * Cdim + c0;
        const int ostep = dir ? -(2 * Cdim) : (2 * Cdim);

        unsigned int rr[PF], kk[PF], vv[PF];
        #pragma unroll
        for (int i = 0; i < PF; ++i) {
            rr[i] = *(const unsigned int*)(q);
            kk[i] = *(const unsigned int*)(q + Cdim);
            vv[i] = *(const unsigned int*)(q + 2 * Cdim);
            q += tstep;
        }
        for (int t = 0; t < LSEG; t += PF) {
            unsigned int rn[PF], kn[PF], vn[PF];
            if (t + PF < LSEG) {
                #pragma unroll
                for (int i = 0; i < PF; ++i) {
                    rn[i] = *(const unsigned int*)(q);
                    kn[i] = *(const unsigned int*)(q + Cdim);
                    vn[i] = *(const unsigned int*)(q + 2 * Cdim);
                    q += tstep;
                }
            }
            #pragma unroll
            for (int i = 0; i < PF; ++i) {
                unsigned int ow;
                {
                    const float k_ = bf2f_lo(kk[i]), v_ = bf2f_lo(vv[i]), r_ = bf2f_lo(rr[i]);
                    const float ku = k_ + u0;
                    const float m  = fmaxf(mx0, ku);
                    const float e1 = __expf(mx0 - m);
                    const float e2 = __expf(ku - m);
                    const float y  = (e1 * num0 + e2 * v_) * frcp(e1 * den0 + e2);
                    const float sr = frcp(1.0f + __expf(-r_));
                    ow = (unsigned int)f2bf(sr * y);
                    const float mw  = mx0 + w0;
                    const float mn  = fmaxf(mw, k_);
                    const float e1s = __expf(mw - mn);
                    const float e2s = __expf(k_ - mn);
                    num0 = e1s * num0 + e2s * v_;
                    den0 = e1s * den0 + e2s;
                    mx0  = mn;
                }
                {
                    const float k_ = bf2f_hi(kk[i]), v_ = bf2f_hi(vv[i]), r_ = bf2f_hi(rr[i]);
                    const float ku = k_ + u1;
                    const float m  = fmaxf(mx1, ku);
                    const float e1 = __expf(mx1 - m);
                    const float e2 = __expf(ku - m);
                    const float y  = (e1 * num1 + e2 * v_) * frcp(e1 * den1 + e2);
                    const float sr = frcp(1.0f + __expf(-r_));
                    ow |= ((unsigned int)f2bf(sr * y)) << 16;
                    const float mw  = mx1 + w1;
                    const float mn  = fmaxf(mw, k_);
                    const float e1s = __expf(mw - mn);
                    const float e2s = __expf(k_ - mn);
                    num1 = e1s * num1 + e2s * v_;
                    den1 = e1s * den1 + e2s;
                    mx1  = mn;
                }
                *(unsigned int*)po = ow;
                po += ostep;
            }
            #pragma unroll
            for (int i = 0; i < PF; ++i) { rr[i] = rn[i]; kk[i] = kn[i]; vv[i] = vn[i]; }
        }
    }
}

// ---------------------------------------------------------------------------
extern "C" void kernel_launch(void* const* d_in, const int* in_sizes, int n_in,
                              void* d_out, int out_size, void* d_ws, size_t ws_size,
                              hipStream_t stream)
{
    const float* x    = (const float*)d_in[0];
    const float* rkvw = (const float*)d_in[1];
    const float* outw = (const float*)d_in[2];
    const float* td   = (const float*)d_in[3];
    const float* tf   = (const float*)d_in[4];
    const float* tdr  = (const float*)d_in[5];
    const float* tfr  = (const float*)d_in[6];
    float* out = (float*)d_out;

    const int M = Bdim * Tdim;   // 8192

    char* ws = (char*)d_ws;
    unsigned short* rkv = (unsigned short*)ws;                 //  96 MiB bf16 [B,T,6C]
    unsigned short* xb  = (unsigned short*)(ws + 100663296);   //  16 MiB bf16 x
    unsigned short* wb  = (unsigned short*)(ws + 117440512);   //  12 MiB bf16 rkv_w
    unsigned short* ob  = (unsigned short*)(ws + 130023424);   //   4 MiB bf16 out_w
    unsigned short* cat = (unsigned short*)(ws + 134217728);   //  32 MiB bf16 out_cat

    const int n1 = M * Cdim / 4;
    const int n2 = 6 * Cdim * Cdim / 4;
    const int n3 = Cdim * 2 * Cdim / 4;

    hipLaunchKernelGGL(cast_all, dim3((n1 + n2 + n3 + 255) / 256), dim3(256), 0, stream,
                       x, xb, n1, rkvw, wb, n2, outw, ob, n3);

    // GEMM1: 256x128 tile, 3-slot, 2 blocks/CU, 2D-chunked XCD order
    hipLaunchKernelGGL(gemm1_3slot, dim3(G1_NWG), dim3(512), 0, stream, xb, wb, rkv);

    // segmented-parallel fused sigmoid + bidirectional WKV scan
    // (R12 config: VC=2, SEG=64, PF=8 both phases; + XCD pair-swizzle)
    hipLaunchKernelGGL(wkv_scan_par, dim3(Bdim * 2 * 32), dim3(1024), 0, stream,
                       rkv, td, tf, tdr, tfr, cat);

    // GEMM2 (m97 128², fp32 out): M=8192, N=1024, K=2048; grid 8x64=512
    hipLaunchKernelGGL(gemm_bf16_nt, dim3(Cdim / 128, M / 128), dim3(256), 0, stream,
                       cat, ob, out, M, Cdim, 2 * Cdim);
}

// Round 18
// 231.400 us; speedup vs baseline: 1.1336x; 1.0036x over previous
//
#include <hip/hip_runtime.h>
#include <cstdint>
#include <cstddef>

#define Bdim 4
#define Tdim 2048
#define Cdim 1024

// scan geometry: block 1024 = 16 ch-groups (x2 channels) x SEG(64) segs of 32
#define SEG  64
#define LSEG (Tdim / SEG)

#define G1_K   1024
#define G1_N   6144
#define G1_NKT 32
#define G1_NWG 1536

typedef __attribute__((ext_vector_type(8))) short bf16x8;
typedef __attribute__((ext_vector_type(4))) float f32x4;

__device__ __forceinline__ unsigned short f2bf(float f) {
    unsigned int u = __float_as_uint(f);
    u += 0x7fffu + ((u >> 16) & 1u);
    return (unsigned short)(u >> 16);
}
__device__ __forceinline__ float bf2f_lo(unsigned int u) {
    return __uint_as_float(u << 16);
}
__device__ __forceinline__ float bf2f_hi(unsigned int u) {
    return __uint_as_float(u & 0xffff0000u);
}
__device__ __forceinline__ float frcp(float x) {
    return __builtin_amdgcn_rcpf(x);
}

__device__ __forceinline__ void gload_lds16(const void* g, void* l) {
    __builtin_amdgcn_global_load_lds(
        (const __attribute__((address_space(1))) unsigned int*)g,
        (__attribute__((address_space(3))) unsigned int*)l,
        16, 0, 0);
}

// ---------------------------------------------------------------------------
// merged fp32 -> bf16 cast of x, rkv_w, out_w
// ---------------------------------------------------------------------------
__global__ __launch_bounds__(256) void cast_all(
    const float* __restrict__ x,  unsigned short* __restrict__ xb,  int n1,
    const float* __restrict__ w1, unsigned short* __restrict__ wb,  int n2,
    const float* __restrict__ w2, unsigned short* __restrict__ ob,  int n3)
{
    int i = blockIdx.x * 256 + threadIdx.x;
    const float* in; unsigned short* out;
    if (i < n1)           { in = x;  out = xb; }
    else if (i < n1 + n2) { in = w1; out = wb; i -= n1; }
    else if (i < n1 + n2 + n3) { in = w2; out = ob; i -= n1 + n2; }
    else return;
    float4 v = ((const float4*)in)[i];
    ushort4 o;
    o.x = f2bf(v.x); o.y = f2bf(v.y); o.z = f2bf(v.z); o.w = f2bf(v.w);
    ((ushort4*)out)[i] = o;
}

// ---------------------------------------------------------------------------
// GEMM1: 256x128 tile, BK=32, 3-slot LDS rotation, 2 blocks/CU, XCD-chunked
// 2D tile order (R11/R12-verified).
// R18 FIX: drain vmcnt(0) before kernel end. The tail phases leave up to 3
// global_load_lds outstanding at s_endpgm; their DMA writes can land in the
// LDS of the NEXT workgroup scheduled on this CU after dealloc/realloc ->
// intermittent corruption (R17's post-timing divergence). Waves must not
// terminate with LDS-writing loads in flight.
// ---------------------------------------------------------------------------
__device__ __forceinline__ void stage_128(
    const unsigned short* __restrict__ G, int row0, int K, int elemoff,
    char* slot, int wave, int lane)
{
    const int sl = (lane & 3) ^ ((lane >> 3) & 3);
    const unsigned short* gp = G + (size_t)(row0 + wave * 16 + (lane >> 2)) * K
                                 + elemoff + sl * 8;
    gload_lds16(gp, slot + wave * 1024);
}

__global__ __launch_bounds__(512, 4) void gemm1_3slot(
    const unsigned short* __restrict__ A, const unsigned short* __restrict__ B,
    unsigned short* __restrict__ C)
{
    __shared__ char ldsb[73728];

    const int tid  = threadIdx.x;
    const int wave = tid >> 6;
    const int lane = tid & 63;
    const int wm = wave >> 1;
    const int wn = wave & 1;
    const int fr = lane & 15;
    const int cswz = (((lane >> 4) ^ ((fr >> 1) & 3)) << 4);

    const int xcd = blockIdx.x & 7;
    const int li  = blockIdx.x >> 3;
    const int bx  = li >> 2;
    const int by  = xcd * 4 + (li & 3);
    const int m0 = by * 256;
    const int n0 = bx * 128;

    f32x4 acc[4][4] = {};

    stage_128(A, m0,       G1_K, 0,  ldsb + 0,            wave, lane);
    stage_128(A, m0 + 128, G1_K, 0,  ldsb + 8192,         wave, lane);
    stage_128(B, n0,       G1_K, 0,  ldsb + 49152,        wave, lane);
    stage_128(A, m0,       G1_K, 32, ldsb + 16384,        wave, lane);
    stage_128(A, m0 + 128, G1_K, 32, ldsb + 16384 + 8192, wave, lane);
    stage_128(B, n0,       G1_K, 32, ldsb + 49152 + 8192, wave, lane);
    asm volatile("s_waitcnt vmcnt(3)" ::: "memory");
    __builtin_amdgcn_s_barrier();
    __builtin_amdgcn_sched_barrier(0);

    int sR = 0;
    for (int t = 0; t < G1_NKT; ++t) {
        const int sW = (sR >= 1) ? sR - 1 : 2;
        int kst = t + 2; if (kst > G1_NKT - 1) kst = G1_NKT - 1;
        const int keoff = kst * 32;

        const char* Asl = ldsb + sR * 16384;
        const char* Bsl = ldsb + 49152 + sR * 8192;

        bf16x8 af[4], bq[4];
        #pragma unroll
        for (int i_ = 0; i_ < 4; ++i_)
            af[i_] = *(const bf16x8*)(Asl + (wm * 64 + i_ * 16 + fr) * 64 + cswz);
        #pragma unroll
        for (int j_ = 0; j_ < 4; ++j_)
            bq[j_] = *(const bf16x8*)(Bsl + (wn * 64 + j_ * 16 + fr) * 64 + cswz);

        stage_128(A, m0,       G1_K, keoff, ldsb + sW * 16384,        wave, lane);
        stage_128(A, m0 + 128, G1_K, keoff, ldsb + sW * 16384 + 8192, wave, lane);
        stage_128(B, n0,       G1_K, keoff, ldsb + 49152 + sW * 8192, wave, lane);

        __builtin_amdgcn_s_barrier();
        __builtin_amdgcn_sched_barrier(0);
        __builtin_amdgcn_s_setprio(1);
        #pragma unroll
        for (int i_ = 0; i_ < 4; ++i_)
            #pragma unroll
            for (int j_ = 0; j_ < 4; ++j_)
                acc[i_][j_] = __builtin_amdgcn_mfma_f32_16x16x32_bf16(
                    af[i_], bq[j_], acc[i_][j_], 0, 0, 0);
        __builtin_amdgcn_s_setprio(0);
        asm volatile("s_waitcnt vmcnt(3)" ::: "memory");
        __builtin_amdgcn_s_barrier();
        __builtin_amdgcn_sched_barrier(0);

        sR = (sR < 2) ? sR + 1 : 0;
    }

    // R18: drain tail global_load_lds before any wave can reach s_endpgm
    asm volatile("s_waitcnt vmcnt(0)" ::: "memory");

    #pragma unroll
    for (int i_ = 0; i_ < 4; ++i_) {
        const int row = m0 + wm * 64 + i_ * 16 + (lane >> 4) * 4;
        #pragma unroll
        for (int j_ = 0; j_ < 4; ++j_) {
            const int col = n0 + wn * 64 + j_ * 16 + fr;
            #pragma unroll
            for (int r = 0; r < 4; ++r)
                C[(size_t)(row + r) * G1_N + col] = f2bf(acc[i_][j_][r]);
        }
    }
}

// ---------------------------------------------------------------------------
// m97-structure 128x128 bf16 GEMM (NT), fp32 out — GEMM2 (grid 512).
// (Safe at exit: final loop iteration's gload_lds are drained by the
// in-loop __syncthreads before the last reads.)
// ---------------------------------------------------------------------------
__global__ __launch_bounds__(256) void gemm_bf16_nt(
    const unsigned short* __restrict__ A, const unsigned short* __restrict__ B,
    float* __restrict__ C, int M, int N, int K)
{
    __shared__ unsigned short As[128 * 32];
    __shared__ unsigned short Bs[128 * 32];

    const int tid  = threadIdx.x;
    const int wave = tid >> 6;
    const int lane = tid & 63;
    const int m0 = blockIdx.y * 128;
    const int n0 = blockIdx.x * 128;
    const int wr = wave >> 1, wc = wave & 1;

    const int srow = tid >> 2;
    const int scol = (tid & 3) * 8;
    const unsigned short* Ag = A + (size_t)(m0 + srow) * K + scol;
    const unsigned short* Bg = B + (size_t)(n0 + srow) * K + scol;
    char* AsW = (char*)As + wave * 1024;
    char* BsW = (char*)Bs + wave * 1024;

    f32x4 acc[4][4] = {};

    const int fr = lane & 15;
    const int fk = (lane >> 4) * 8;

    for (int k0 = 0; k0 < K; k0 += 32) {
        gload_lds16(Ag + k0,                  AsW);
        gload_lds16(Ag + k0 + (size_t)64 * K, AsW + 4096);
        gload_lds16(Bg + k0,                  BsW);
        gload_lds16(Bg + k0 + (size_t)64 * K, BsW + 4096);
        __syncthreads();

        bf16x8 af[4], bfr_[4];
        #pragma unroll
        for (int f = 0; f < 4; ++f) {
            af[f]   = *(const bf16x8*)&As[(wr * 64 + f * 16 + fr) * 32 + fk];
            bfr_[f] = *(const bf16x8*)&Bs[(wc * 64 + f * 16 + fr) * 32 + fk];
        }
        #pragma unroll
        for (int i = 0; i < 4; ++i)
            #pragma unroll
            for (int j = 0; j < 4; ++j)
                acc[i][j] = __builtin_amdgcn_mfma_f32_16x16x32_bf16(
                    af[i], bfr_[j], acc[i][j], 0, 0, 0);
        __syncthreads();
    }

    #pragma unroll
    for (int i = 0; i < 4; ++i) {
        const int row = m0 + wr * 64 + i * 16 + (lane >> 4) * 4;
        #pragma unroll
        for (int j = 0; j < 4; ++j) {
            const int col = n0 + wc * 64 + j * 16 + (lane & 15);
            #pragma unroll
            for (int r = 0; r < 4; ++r)
                C[(size_t)(row + r) * N + col] = acc[i][j][r];
        }
    }
}

// ---------------------------------------------------------------------------
// Segmented-parallel fused sigmoid(r)*WKV scan, bf16 in/out, VC=2, SEG=64.
// EXACT R16 (best passing, 232.2us): PF=8 both phases, XCD pair-swizzle.
// ---------------------------------------------------------------------------
__global__ __launch_bounds__(1024) void wkv_scan_par(
    const unsigned short* __restrict__ rkv,
    const float* __restrict__ td,  const float* __restrict__ tf,
    const float* __restrict__ tdr, const float* __restrict__ tfr,
    unsigned short* __restrict__ outcat)
{
    __shared__ float sBn[SEG][32], sBd[SEG][32], sMb[SEG][32];

    const int tid = threadIdx.x;
    const int chg = tid & 15;            // channel group (2 channels)
    const int seg = tid >> 4;            // 0..63

    // XCD pair-swizzle (R16-verified): blocks covering adjacent 64B halves
    // of each 128B L2 line land on the same XCD (bijective remap).
    const int xcd  = blockIdx.x & 7;
    const int slot = blockIdx.x >> 3;            // 0..63
    const int bi   = (((slot >> 1) * 8 + xcd) << 1) | (slot & 1);

    const int b   = bi >> 6;
    const int rem = bi & 63;
    const int dir = rem >> 5;
    const int cbase = (rem & 31) * 32;   // block's first channel
    const int c0  = cbase + chg * 2;     // this thread's channels c0, c0+1

    const float w0 = -__expf(dir ? tdr[c0]     : td[c0]);
    const float w1 = -__expf(dir ? tdr[c0 + 1] : td[c0 + 1]);
    const float u0 = dir ? tfr[c0]     : tf[c0];
    const float u1 = dir ? tfr[c0 + 1] : tf[c0 + 1];

    const int strideT = 6 * Cdim;
    const int tstep   = dir ? -strideT : strideT;
    const int t0      = dir ? (Tdim - 1 - seg * LSEG) : (seg * LSEG);

    const unsigned short* pbase = rkv + ((size_t)b * Tdim + t0) * strideT + dir * 3 * Cdim + c0;

    const int PF = 8;

    // ---- phase 1: segment-local summary (k,v only) ----
    float bn0 = 0.f, bd0 = 0.f, mb0 = -1e38f;
    float bn1 = 0.f, bd1 = 0.f, mb1 = -1e38f;
    {
        const unsigned short* q = pbase;
        unsigned int kk[PF], vv[PF];
        #pragma unroll
        for (int i = 0; i < PF; ++i) {
            kk[i] = *(const unsigned int*)(q + Cdim);
            vv[i] = *(const unsigned int*)(q + 2 * Cdim);
            q += tstep;
        }
        for (int t = 0; t < LSEG; t += PF) {
            unsigned int kn[PF], vn[PF];
            if (t + PF < LSEG) {
                #pragma unroll
                for (int i = 0; i < PF; ++i) {
                    kn[i] = *(const unsigned int*)(q + Cdim);
                    vn[i] = *(const unsigned int*)(q + 2 * Cdim);
                    q += tstep;
                }
            }
            #pragma unroll
            for (int i = 0; i < PF; ++i) {
                {
                    const float k_ = bf2f_lo(kk[i]), v_ = bf2f_lo(vv[i]);
                    const float mw = mb0 + w0;
                    const float mn = fmaxf(mw, k_);
                    const float e1 = __expf(mw - mn);
                    const float e2 = __expf(k_ - mn);
                    bn0 = e1 * bn0 + e2 * v_;
                    bd0 = e1 * bd0 + e2;
                    mb0 = mn;
                }
                {
                    const float k_ = bf2f_hi(kk[i]), v_ = bf2f_hi(vv[i]);
                    const float mw = mb1 + w1;
                    const float mn = fmaxf(mw, k_);
                    const float e1 = __expf(mw - mn);
                    const float e2 = __expf(k_ - mn);
                    bn1 = e1 * bn1 + e2 * v_;
                    bd1 = e1 * bd1 + e2;
                    mb1 = mn;
                }
            }
            #pragma unroll
            for (int i = 0; i < PF; ++i) { kk[i] = kn[i]; vv[i] = vn[i]; }
        }
    }
    sBn[seg][chg * 2] = bn0; sBd[seg][chg * 2] = bd0; sMb[seg][chg * 2] = mb0;
    sBn[seg][chg * 2 + 1] = bn1; sBd[seg][chg * 2 + 1] = bd1; sMb[seg][chg * 2 + 1] = mb1;
    __syncthreads();

    // ---- phase 2: exclusive combine over 64 segments (32 lanes) ----
    if (tid < 32) {
        const float wv = -__expf(dir ? tdr[cbase + tid] : td[cbase + tid]);
        const float a  = wv * (float)LSEG;
        float n = 0.f, d = 0.f, m = -1e38f;
        for (int s = 0; s < SEG; ++s) {
            const float tn = sBn[s][tid], tdn = sBd[s][tid], tm = sMb[s][tid];
            sBn[s][tid] = n; sBd[s][tid] = d; sMb[s][tid] = m;
            const float ma = m + a;
            const float mm = fmaxf(ma, tm);
            const float e1 = __expf(ma - mm);
            const float e2 = __expf(tm - mm);
            n = e1 * n + e2 * tn;
            d = e1 * d + e2 * tdn;
            m = mm;
        }
    }
    __syncthreads();

    // ---- phase 3: replay segment from prefix, emit outputs (PF=8) ----
    float num0 = sBn[seg][chg * 2],     den0 = sBd[seg][chg * 2],     mx0 = sMb[seg][chg * 2];
    float num1 = sBn[seg][chg * 2 + 1], den1 = sBd[seg][chg * 2 + 1], mx1 = sMb[seg][chg * 2 + 1];
    {
        const unsigned short* q = pbase;
        unsigned short* po = outcat + ((size_t)b * Tdim + t0) * (2 * Cdim) + dir * Cdim + c0;
        const int ostep = dir ? -(2 * Cdim) : (2 * Cdim);

        unsigned int rr[PF], kk[PF], vv[PF];
        #pragma unroll
        for (int i = 0; i < PF; ++i) {
            rr[i] = *(const unsigned int*)(q);
            kk[i] = *(const unsigned int*)(q + Cdim);
            vv[i] = *(const unsigned int*)(q + 2 * Cdim);
            q += tstep;
        }
        for (int t = 0; t < LSEG; t += PF) {
            unsigned int rn[PF], kn[PF], vn[PF];
            if (t + PF < LSEG) {
                #pragma unroll
                for (int i = 0; i < PF; ++i) {
                    rn[i] = *(const unsigned int*)(q);
                    kn[i] = *(const unsigned int*)(q + Cdim);
                    vn[i] = *(const unsigned int*)(q + 2 * Cdim);
                    q += tstep;
                }
            }
            #pragma unroll
            for (int i = 0; i < PF; ++i) {
                unsigned int ow;
                {
                    const float k_ = bf2f_lo(kk[i]), v_ = bf2f_lo(vv[i]), r_ = bf2f_lo(rr[i]);
                    const float ku = k_ + u0;
                    const float m  = fmaxf(mx0, ku);
                    const float e1 = __expf(mx0 - m);
                    const float e2 = __expf(ku - m);
                    const float y  = (e1 * num0 + e2 * v_) * frcp(e1 * den0 + e2);
                    const float sr = frcp(1.0f + __expf(-r_));
                    ow = (unsigned int)f2bf(sr * y);
                    const float mw  = mx0 + w0;
                    const float mn  = fmaxf(mw, k_);
                    const float e1s = __expf(mw - mn);
                    const float e2s = __expf(k_ - mn);
                    num0 = e1s * num0 + e2s * v_;
                    den0 = e1s * den0 + e2s;
                    mx0  = mn;
                }
                {
                    const float k_ = bf2f_hi(kk[i]), v_ = bf2f_hi(vv[i]), r_ = bf2f_hi(rr[i]);
                    const float ku = k_ + u1;
                    const float m  = fmaxf(mx1, ku);
                    const float e1 = __expf(mx1 - m);
                    const float e2 = __expf(ku - m);
                    const float y  = (e1 * num1 + e2 * v_) * frcp(e1 * den1 + e2);
                    const float sr = frcp(1.0f + __expf(-r_));
                    ow |= ((unsigned int)f2bf(sr * y)) << 16;
                    const float mw  = mx1 + w1;
                    const float mn  = fmaxf(mw, k_);
                    const float e1s = __expf(mw - mn);
                    const float e2s = __expf(k_ - mn);
                    num1 = e1s * num1 + e2s * v_;
                    den1 = e1s * den1 + e2s;
                    mx1  = mn;
                }
                *(unsigned int*)po = ow;
                po += ostep;
            }
            #pragma unroll
            for (int i = 0; i < PF; ++i) { rr[i] = rn[i]; kk[i] = kn[i]; vv[i] = vn[i]; }
        }
    }
}

// ---------------------------------------------------------------------------
extern "C" void kernel_launch(void* const* d_in, const int* in_sizes, int n_in,
                              void* d_out, int out_size, void* d_ws, size_t ws_size,
                              hipStream_t stream)
{
    const float* x    = (const float*)d_in[0];
    const float* rkvw = (const float*)d_in[1];
    const float* outw = (const float*)d_in[2];
    const float* td   = (const float*)d_in[3];
    const float* tf   = (const float*)d_in[4];
    const float* tdr  = (const float*)d_in[5];
    const float* tfr  = (const float*)d_in[6];
    float* out = (float*)d_out;

    const int M = Bdim * Tdim;   // 8192

    char* ws = (char*)d_ws;
    unsigned short* rkv = (unsigned short*)ws;                 //  96 MiB bf16 [B,T,6C]
    unsigned short* xb  = (unsigned short*)(ws + 100663296);   //  16 MiB bf16 x
    unsigned short* wb  = (unsigned short*)(ws + 117440512);   //  12 MiB bf16 rkv_w
    unsigned short* ob  = (unsigned short*)(ws + 130023424);   //   4 MiB bf16 out_w
    unsigned short* cat = (unsigned short*)(ws + 134217728);   //  32 MiB bf16 out_cat

    const int n1 = M * Cdim / 4;
    const int n2 = 6 * Cdim * Cdim / 4;
    const int n3 = Cdim * 2 * Cdim / 4;

    hipLaunchKernelGGL(cast_all, dim3((n1 + n2 + n3 + 255) / 256), dim3(256), 0, stream,
                       x, xb, n1, rkvw, wb, n2, outw, ob, n3);

    // GEMM1: 256x128 tile, 3-slot, 2 blocks/CU, 2D-chunked XCD order (+drain)
    hipLaunchKernelGGL(gemm1_3slot, dim3(G1_NWG), dim3(512), 0, stream, xb, wb, rkv);

    // scan: R16 config (VC=2, SEG=64, PF=8 both phases, XCD pair-swizzle)
    hipLaunchKernelGGL(wkv_scan_par, dim3(Bdim * 2 * 32), dim3(1024), 0, stream,
                       rkv, td, tf, tdr, tfr, cat);

    // GEMM2 (m97 128², fp32 out): M=8192, N=1024, K=2048; grid 8x64=512
    hipLaunchKernelGGL(gemm_bf16_nt, dim3(Cdim / 128, M / 128), dim3(256), 0, stream,
                       cat, ob, out, M, Cdim, 2 * Cdim);
}